// Round 11
// baseline (34.672 us; speedup 1.0000x reference)
//
#include <hip/hip_runtime.h>
#include <math.h>

#define NTOT 131072
#define NSIG 64
#define SEGL 2048
#define NIN 256

// ws layout (bytes):
//   [0, 524288)         y0[131072] f32 (rows 0..127 partial)
//   [524288, 1048576)   y1[131072] f32 (rows 128..255 partial)
//   [1048576, 1572864)  w_all[64][2048] f32 (only [1024-D, 1024+min(D,1023)] written)
//   [1572864, 1573120)  Dv[64] int
// Truncation: taps beyond |d| = 12|sigma|+4 are exp(<-72) == 0 in f32 and
// Z >= 1 (peak tap exp(0)=1), so truncation error ~1e-28 absolute.

// ---------------------------------------------------------------------------
// K1: split-K=2 ACROSS BLOCKS: 1024 blocks x 256 threads = 16 waves/CU
// (2x the TLP of thread-per-column; 4096 concurrent wave-streams).
// Block bx: chunk = bx>>1 (256 cols), half = bx&1 (128 rows). Thread t
// accumulates col chunk*256+t over its 128 rows -> y{half}[col]. No in-block
// combine (k_conv sums y0+y1+b3 during staging). Branch-free scalar stream.
// Duty blocks (bx0 < 64, one per segment, spread over all XCDs) additionally
// run the full MLP dot (W1 L2-resident) -> sigma -> truncated window.
// ---------------------------------------------------------------------------
__global__ __launch_bounds__(256) void k_y(
    const float* __restrict__ x,  const float* __restrict__ W1,
    const float* __restrict__ b1, const float* __restrict__ W2,
    const float* __restrict__ b2, const float* __restrict__ W3,
    float* __restrict__ y01, float* __restrict__ w_all, int* __restrict__ Dv)
{
  __shared__ float xl[NIN];
  __shared__ float sl[256];
  __shared__ float red[4];
  __shared__ float bc[2];

  const int t = threadIdx.x;
  const int bx0 = (int)blockIdx.x;
  // bijective XCD swizzle: 128 consecutive bx per XCD
  const int bx = ((bx0 & 7) << 7) | (bx0 >> 3);
  const int chunk = bx >> 1;
  const int half = bx & 1;
  const int col = (chunk << 8) + t;

  xl[t] = x[t];
  __syncthreads();

  // ---- half-K stream: 128 scalar rows, branch-free ----
  const float* p = W3 + (size_t)(half << 7) * NTOT + col;
  float a = 0.0f;
  #pragma unroll 16
  for (int k = 0; k < 128; ++k)
    a = fmaf(xl[(half << 7) + k], p[(size_t)k * NTOT], a);
  y01[half * NTOT + col] = a;

  if (bx0 >= NSIG) return;

  // ---- duty block (segment seg = bx0): full MLP -> sigma -> window ----
  const int seg = bx0;
  float am = b1[t];
  #pragma unroll 16
  for (int n = 0; n < NIN; ++n) am = fmaf(xl[n], W1[n * 256 + t], am);
  sl[t] = am / (1.0f + expf(-am));
  __syncthreads();

  float v = sl[t] * W2[t * NSIG + seg];
  #pragma unroll
  for (int o = 32; o > 0; o >>= 1) v += __shfl_down(v, o, 64);
  const int lane = t & 63, wid = t >> 6;
  if (lane == 0) red[wid] = v;
  __syncthreads();
  if (t == 0) bc[0] = red[0] + red[1] + red[2] + red[3] + b2[seg];
  __syncthreads();
  const float sig = bc[0];

  const float inv2 = 1.0f / (2.0f * sig * sig);
  const float Df = 12.0f * fabsf(sig) + 4.0f;
  const int D = (Df >= 1024.0f) ? 1024 : (int)Df;
  const int dlo = -D;
  const int dhi = (D < 1023) ? D : 1023;
  const int cnt = dhi - dlo + 1;

  float zp = 0.0f;
  for (int i = t; i < cnt; i += 256) {
    const float d = (float)(dlo + i);
    const float e = expf(-d * d * inv2);
    w_all[seg * SEGL + 1024 + dlo + i] = e;
    zp += e;
  }
  v = zp;
  #pragma unroll
  for (int o = 32; o > 0; o >>= 1) v += __shfl_down(v, o, 64);
  if (lane == 0) red[wid] = v;
  __syncthreads();
  if (t == 0) bc[1] = red[0] + red[1] + red[2] + red[3];
  __syncthreads();
  const float iZ = 1.0f / bc[1];
  for (int i = t; i < cnt; i += 256)
    w_all[seg * SEGL + 1024 + dlo + i] *= iZ;
  if (t == 0) Dv[seg] = D;
}

// ---------------------------------------------------------------------------
// K2: truncated "same" conv (R5-verbatim except staging sums y0+y1+b3).
// 512 blocks x 256 threads; block bx handles [seg*2048 + M0, +256).
// out[m] = sum_d w[1024+d] * seg[m-1-d], d in [-D, min(D,1023)]
// ---------------------------------------------------------------------------
__global__ __launch_bounds__(256) void k_conv(
    const float* __restrict__ y01, const float* __restrict__ b3,
    const float* __restrict__ w_all, const int* __restrict__ Dv,
    float* __restrict__ out)
{
  __shared__ float S[2560];   // seg coord = sbase + idx

  const int t = threadIdx.x;
  const int bx0 = (int)blockIdx.x;
  const int bx = ((bx0 & 7) << 6) | (bx0 >> 3);
  const int seg = bx >> 3;
  const int M0 = (bx & 7) << 8;
  const int sbase = M0 - 1026;

  const int D = Dv[seg];
  const int dlo = -D;
  const int dhi = (D < 1023) ? D : 1023;

  // live span of S: [1025-dhi, 1281+D)
  const int ilo = 1025 - dhi;
  const int ihi = 1281 + D;
  for (int i = ilo + t; i < ihi; i += 256) {
    const int g = sbase + i;
    float v = 0.0f;
    if (g >= 0 && g < SEGL) {
      const int idx = seg * SEGL + g;
      v = y01[idx] + y01[NTOT + idx] + b3[idx];
    }
    S[i] = v;
  }
  __syncthreads();

  const float* wrow = w_all + seg * SEGL + 1024;
  float a = 0.0f;
  for (int d = dlo; d <= dhi; ++d)
    a = fmaf(wrow[d], S[t + 1025 - d], a);   // wrow[d] block-uniform
  out[seg * SEGL + M0 + t] = a;
}

// ---------------------------------------------------------------------------
extern "C" void kernel_launch(void* const* d_in, const int* in_sizes, int n_in,
                              void* d_out, int out_size, void* d_ws, size_t ws_size,
                              hipStream_t stream) {
  const float* x  = (const float*)d_in[0];
  const float* W1 = (const float*)d_in[1];
  const float* b1 = (const float*)d_in[2];
  const float* W2 = (const float*)d_in[3];
  const float* b2 = (const float*)d_in[4];
  const float* W3 = (const float*)d_in[5];
  const float* b3 = (const float*)d_in[6];
  float* out = (float*)d_out;

  char* ws = (char*)d_ws;
  float* y01   = (float*)(ws);
  float* w_all = (float*)(ws + 1048576);
  int*   Dv    = (int*)  (ws + 1572864);

  hipLaunchKernelGGL(k_y, dim3(1024), dim3(256), 0, stream,
                     x, W1, b1, W2, b2, W3, y01, w_all, Dv);
  hipLaunchKernelGGL(k_conv, dim3(512), dim3(256), 0, stream,
                     y01, b3, w_all, Dv, out);
}

// Round 12
// 32.774 us; speedup vs baseline: 1.0579x; 1.0579x over previous
//
#include <hip/hip_runtime.h>
#include <math.h>

#define NTOT 131072
#define NSIG 64
#define SEGL 2048
#define NIN 256

// ws layout (bytes):
//   [0, 524288)        y[131072] f32
//   [524288, 1048576)  w_all[64][2048] f32 (only [1024-D, 1024+min(D,1023)] written)
//   [1048576, 1048832) Dv[64] int
// Truncation: taps beyond |d| = 12|sigma|+4 are exp(<-72) == 0 in f32 and
// Z >= 1 (peak tap exp(0)=1), so truncation error ~1e-28 absolute.

// ---------------------------------------------------------------------------
// K1: y = x@W3 + b3, thread-per-column scalar stream (the twice-measured-best
// form), but 256 blocks x 512 threads: 2KB contiguous per (block,row) visit
// (vs 1KB before) to halve DRAM page-activation rate; still 8 waves/CU and
// exactly 1 block/CU (all 256 blocks resident). Duty blocks (bx0 < 64) fold
// the MLP dot into the same loop BRANCH-FREE: lanes >= 256 redundantly
// compute dot (t&255) (same W1 addresses as lanes 0..255 -> L2 broadcast),
// then sigma -> truncated normalized window for segment bx0.
// ---------------------------------------------------------------------------
__global__ __launch_bounds__(512) void k_y(
    const float* __restrict__ x,  const float* __restrict__ W1,
    const float* __restrict__ b1, const float* __restrict__ W2,
    const float* __restrict__ b2, const float* __restrict__ W3,
    const float* __restrict__ b3, float* __restrict__ y,
    float* __restrict__ w_all, int* __restrict__ Dv)
{
  __shared__ float xl[NIN];
  __shared__ float sl[256];
  __shared__ float red[8];
  __shared__ float bc[2];

  const int t = threadIdx.x;
  const int bx0 = (int)blockIdx.x;
  // bijective XCD swizzle: 32 consecutive 512-col strips per XCD
  const int bx = ((bx0 & 7) << 5) | (bx0 >> 3);
  const int col = (bx << 9) + t;

  if (t < NIN) xl[t] = x[t];
  __syncthreads();

  const float* p = W3 + col;
  float a = b3[col];
  const int lane = t & 63, wid = t >> 6;

  if (bx0 < NSIG) {
    // ---- duty block: matvec + (redundant-above-256) MLP dot, branch-free --
    const int h = t & 255;
    float am = b1[h];
    #pragma unroll 16
    for (int n = 0; n < NIN; ++n) {
      const float xv = xl[n];
      a  = fmaf(xv, p[(size_t)n * NTOT], a);
      am = fmaf(xv, W1[n * 256 + h], am);
    }
    y[col] = a;
    if (t < 256) sl[t] = am / (1.0f + expf(-am));
    __syncthreads();

    // ---- sigma = s @ W2[:,seg] + b2[seg] (256 lanes active) ----
    const int seg = bx0;
    if (t < 256) {
      float v = sl[t] * W2[t * NSIG + seg];
      #pragma unroll
      for (int o = 32; o > 0; o >>= 1) v += __shfl_down(v, o, 64);
      if (lane == 0) red[wid] = v;
    }
    __syncthreads();
    if (t == 0) bc[0] = red[0] + red[1] + red[2] + red[3] + b2[seg];
    __syncthreads();
    const float sig = bc[0];

    // ---- truncated gaussian window (all 512 threads) ----
    const float inv2 = 1.0f / (2.0f * sig * sig);
    const float Df = 12.0f * fabsf(sig) + 4.0f;
    const int D = (Df >= 1024.0f) ? 1024 : (int)Df;
    const int dlo = -D;
    const int dhi = (D < 1023) ? D : 1023;
    const int cnt = dhi - dlo + 1;

    float zp = 0.0f;
    for (int i = t; i < cnt; i += 512) {
      const float d = (float)(dlo + i);
      const float e = expf(-d * d * inv2);
      w_all[seg * SEGL + 1024 + dlo + i] = e;
      zp += e;
    }
    float v = zp;
    #pragma unroll
    for (int o = 32; o > 0; o >>= 1) v += __shfl_down(v, o, 64);
    if (lane == 0) red[wid] = v;
    __syncthreads();
    if (t == 0) bc[1] = red[0] + red[1] + red[2] + red[3]
                      + red[4] + red[5] + red[6] + red[7];
    __syncthreads();
    const float iZ = 1.0f / bc[1];
    for (int i = t; i < cnt; i += 512)
      w_all[seg * SEGL + 1024 + dlo + i] *= iZ;
    if (t == 0) Dv[seg] = D;
  } else {
    // ---- pure stream ----
    #pragma unroll 16
    for (int n = 0; n < NIN; ++n)
      a = fmaf(xl[n], p[(size_t)n * NTOT], a);
    y[col] = a;
  }
}

// ---------------------------------------------------------------------------
// K2: truncated "same" conv (verbatim from the 31.8us-best config).
// 512 blocks x 256 threads; block bx handles [seg*2048 + M0, +256).
// Stages only the live y span; window read directly (block-uniform scalar).
// out[m] = sum_d w[1024+d] * seg[m-1-d], d in [-D, min(D,1023)]
// ---------------------------------------------------------------------------
__global__ __launch_bounds__(256) void k_conv(
    const float* __restrict__ y, const float* __restrict__ w_all,
    const int* __restrict__ Dv, float* __restrict__ out)
{
  __shared__ float S[2560];   // seg coord = sbase + idx

  const int t = threadIdx.x;
  const int bx0 = (int)blockIdx.x;
  const int bx = ((bx0 & 7) << 6) | (bx0 >> 3);   // same XCD as producer
  const int seg = bx >> 3;
  const int M0 = (bx & 7) << 8;
  const int sbase = M0 - 1026;

  const int D = Dv[seg];
  const int dlo = -D;
  const int dhi = (D < 1023) ? D : 1023;

  // live span of S: [1025-dhi, 1281+D)
  const int ilo = 1025 - dhi;
  const int ihi = 1281 + D;
  for (int i = ilo + t; i < ihi; i += 256) {
    const int g = sbase + i;
    S[i] = (g >= 0 && g < SEGL) ? y[seg * SEGL + g] : 0.0f;
  }
  __syncthreads();

  const float* wrow = w_all + seg * SEGL + 1024;
  float a = 0.0f;
  for (int d = dlo; d <= dhi; ++d)
    a = fmaf(wrow[d], S[t + 1025 - d], a);   // wrow[d] block-uniform
  out[seg * SEGL + M0 + t] = a;
}

// ---------------------------------------------------------------------------
extern "C" void kernel_launch(void* const* d_in, const int* in_sizes, int n_in,
                              void* d_out, int out_size, void* d_ws, size_t ws_size,
                              hipStream_t stream) {
  const float* x  = (const float*)d_in[0];
  const float* W1 = (const float*)d_in[1];
  const float* b1 = (const float*)d_in[2];
  const float* W2 = (const float*)d_in[3];
  const float* b2 = (const float*)d_in[4];
  const float* W3 = (const float*)d_in[5];
  const float* b3 = (const float*)d_in[6];
  float* out = (float*)d_out;

  char* ws = (char*)d_ws;
  float* y     = (float*)(ws);
  float* w_all = (float*)(ws + 524288);
  int*   Dv    = (int*)  (ws + 1048576);

  hipLaunchKernelGGL(k_y, dim3(256), dim3(512), 0, stream,
                     x, W1, b1, W2, b2, W3, b3, y, w_all, Dv);
  hipLaunchKernelGGL(k_conv, dim3(512), dim3(256), 0, stream,
                     y, w_all, Dv, out);
}

// Round 13
// 31.228 us; speedup vs baseline: 1.1103x; 1.0495x over previous
//
#include <hip/hip_runtime.h>
#include <math.h>

#define NTOT 131072
#define NSIG 64
#define SEGL 2048
#define NIN 256

// ws layout (bytes):
//   [0, 524288)        y[131072] f32
//   [524288, 1048576)  w_all[64][2048] f32 (only [1024-D, 1024+min(D,1023)] written)
//   [1048576, 1048832) Dv[64] int
// Truncation: taps beyond |d| = 12|sigma|+4 are exp(<-72) == 0 in f32 and
// Z >= 1 (peak tap exp(0)=1), so truncation error ~1e-28 absolute.

// ---------------------------------------------------------------------------
// K1: y = x@W3 + b3 (R5-best structure, verbatim) with ONE change:
// __builtin_nontemporal_load on the zero-reuse W3 stream (bypass L1/L2
// allocation; W1/W2/b3 keep normal caching). 512 blocks x 256 threads,
// 2 blocks/CU, 8 waves/CU, thread-per-column scalar unroll-16, branch-free.
// Duty blocks (bx0 < 64) fold the MLP dot into the same loop, then
// sigma -> truncated normalized window for segment bx0.
// ---------------------------------------------------------------------------
__global__ __launch_bounds__(256) void k_y(
    const float* __restrict__ x,  const float* __restrict__ W1,
    const float* __restrict__ b1, const float* __restrict__ W2,
    const float* __restrict__ b2, const float* __restrict__ W3,
    const float* __restrict__ b3, float* __restrict__ y,
    float* __restrict__ w_all, int* __restrict__ Dv)
{
  __shared__ float xl[NIN];
  __shared__ float sl[256];
  __shared__ float red[4];
  __shared__ float bc[2];

  const int t = threadIdx.x;
  const int bx0 = (int)blockIdx.x;
  // bijective XCD swizzle: 64 consecutive 256-col chunks per XCD
  const int bx = ((bx0 & 7) << 6) | (bx0 >> 3);
  const int col = (bx << 8) + t;

  xl[t] = x[t];
  __syncthreads();

  const float* p = W3 + col;
  float a = b3[col];

  if (bx0 < NSIG) {
    // ---- duty block: matvec + MLP in one loop ----
    float am = b1[t];
    #pragma unroll 16
    for (int n = 0; n < NIN; ++n) {
      const float xv = xl[n];
      a  = fmaf(xv, __builtin_nontemporal_load(p + (size_t)n * NTOT), a);
      am = fmaf(xv, W1[n * 256 + t], am);
    }
    y[col] = a;
    sl[t] = am / (1.0f + expf(-am));
    __syncthreads();

    const int seg = bx0;
    float v = sl[t] * W2[t * NSIG + seg];
    #pragma unroll
    for (int o = 32; o > 0; o >>= 1) v += __shfl_down(v, o, 64);
    const int lane = t & 63, wid = t >> 6;
    if (lane == 0) red[wid] = v;
    __syncthreads();
    if (t == 0) bc[0] = red[0] + red[1] + red[2] + red[3] + b2[seg];
    __syncthreads();
    const float sig = bc[0];

    const float inv2 = 1.0f / (2.0f * sig * sig);
    const float Df = 12.0f * fabsf(sig) + 4.0f;
    const int D = (Df >= 1024.0f) ? 1024 : (int)Df;
    const int dlo = -D;
    const int dhi = (D < 1023) ? D : 1023;
    const int cnt = dhi - dlo + 1;

    float zp = 0.0f;
    for (int i = t; i < cnt; i += 256) {
      const float d = (float)(dlo + i);
      const float e = expf(-d * d * inv2);
      w_all[seg * SEGL + 1024 + dlo + i] = e;
      zp += e;
    }
    v = zp;
    #pragma unroll
    for (int o = 32; o > 0; o >>= 1) v += __shfl_down(v, o, 64);
    if (lane == 0) red[wid] = v;
    __syncthreads();
    if (t == 0) bc[1] = red[0] + red[1] + red[2] + red[3];
    __syncthreads();
    const float iZ = 1.0f / bc[1];
    for (int i = t; i < cnt; i += 256)
      w_all[seg * SEGL + 1024 + dlo + i] *= iZ;
    if (t == 0) Dv[seg] = D;
  } else {
    // ---- pure stream ----
    #pragma unroll 16
    for (int n = 0; n < NIN; ++n)
      a = fmaf(xl[n], __builtin_nontemporal_load(p + (size_t)n * NTOT), a);
    y[col] = a;
  }
}

// ---------------------------------------------------------------------------
// K2: truncated "same" conv (verbatim from the 31.8us-best config).
// 512 blocks x 256 threads; block bx handles [seg*2048 + M0, +256).
// Stages only the live y span; window read directly (block-uniform scalar).
// out[m] = sum_d w[1024+d] * seg[m-1-d], d in [-D, min(D,1023)]
// ---------------------------------------------------------------------------
__global__ __launch_bounds__(256) void k_conv(
    const float* __restrict__ y, const float* __restrict__ w_all,
    const int* __restrict__ Dv, float* __restrict__ out)
{
  __shared__ float S[2560];   // seg coord = sbase + idx

  const int t = threadIdx.x;
  const int bx0 = (int)blockIdx.x;
  const int bx = ((bx0 & 7) << 6) | (bx0 >> 3);   // same XCD as producer
  const int seg = bx >> 3;
  const int M0 = (bx & 7) << 8;
  const int sbase = M0 - 1026;

  const int D = Dv[seg];
  const int dlo = -D;
  const int dhi = (D < 1023) ? D : 1023;

  // live span of S: [1025-dhi, 1281+D)
  const int ilo = 1025 - dhi;
  const int ihi = 1281 + D;
  for (int i = ilo + t; i < ihi; i += 256) {
    const int g = sbase + i;
    S[i] = (g >= 0 && g < SEGL) ? y[seg * SEGL + g] : 0.0f;
  }
  __syncthreads();

  const float* wrow = w_all + seg * SEGL + 1024;
  float a = 0.0f;
  for (int d = dlo; d <= dhi; ++d)
    a = fmaf(wrow[d], S[t + 1025 - d], a);   // wrow[d] block-uniform
  out[seg * SEGL + M0 + t] = a;
}

// ---------------------------------------------------------------------------
extern "C" void kernel_launch(void* const* d_in, const int* in_sizes, int n_in,
                              void* d_out, int out_size, void* d_ws, size_t ws_size,
                              hipStream_t stream) {
  const float* x  = (const float*)d_in[0];
  const float* W1 = (const float*)d_in[1];
  const float* b1 = (const float*)d_in[2];
  const float* W2 = (const float*)d_in[3];
  const float* b2 = (const float*)d_in[4];
  const float* W3 = (const float*)d_in[5];
  const float* b3 = (const float*)d_in[6];
  float* out = (float*)d_out;

  char* ws = (char*)d_ws;
  float* y     = (float*)(ws);
  float* w_all = (float*)(ws + 524288);
  int*   Dv    = (int*)  (ws + 1048576);

  hipLaunchKernelGGL(k_y, dim3(512), dim3(256), 0, stream,
                     x, W1, b1, W2, b2, W3, b3, y, w_all, Dv);
  hipLaunchKernelGGL(k_conv, dim3(512), dim3(256), 0, stream,
                     y, w_all, Dv, out);
}